// Round 3
// baseline (88.987 us; speedup 1.0000x reference)
//
#include <hip/hip_runtime.h>

#define B_SZ 1024
#define F_SZ 512
#define NK   50
#define KD   5
#define C_SZ 250            // NK*KD
#define OUTW 562            // F_SZ + NK
#define WSTR 8              // padded KD stride in M planes
#define M_PLANE (NK * B_SZ * WSTR)     // 409600 floats = 1.6384 MB per k-split plane
#define JSPLIT 16
#define LOG2E 1.44269504088896340736f

// ---------------------------------------------------------------------------
// K1: fused GEMM + copy. grid 384 x 256 threads.
//   blocks [0,256):   M = x @ T (fp32 vector), scaled by log2(e), written to
//                     two k-split planes ws2[ks][NK][B][WSTR] (no atomics).
//                     rt = blk&127 (8 rows), ks = blk>>7 (256 f each).
//                     x reads block-uniform -> s_loads; T reads coalesced.
//   blocks [256,384): copy x rows into out (float2) + zero 50 feature cols
//                     (pair_kernel accumulates into them atomically).
// ---------------------------------------------------------------------------
__global__ __launch_bounds__(256) void gemm_copy_kernel(const float* __restrict__ x,
                                                        const float* __restrict__ T,
                                                        float* __restrict__ ws2,
                                                        float* __restrict__ out) {
    const int t = threadIdx.x;

    if (blockIdx.x >= 256) {                 // ---- copy path: 8 rows/block
        const int b = blockIdx.x - 256;      // 0..127
#pragma unroll
        for (int r = 0; r < 8; ++r) {
            const int row = b * 8 + r;
            const float2* src = (const float2*)(x + (size_t)row * F_SZ);
            float2* dst = (float2*)(out + (size_t)row * OUTW);   // 8B aligned
            dst[t] = src[t];                 // 256 float2 = 512 floats
            if (t < NK) out[(size_t)row * OUTW + F_SZ + t] = 0.0f;
        }
        return;
    }

    // ---- gemm path
    const int rt = blockIdx.x & 127;         // row tile (8 rows)
    const int ks = blockIdx.x >> 7;          // k-split (0,1)
    if (t >= C_SZ) return;                   // no __syncthreads in this path
    const int r0 = rt * 8;
    const int f0 = ks * 256;
    const int k = t / KD;
    const int d = t - KD * k;

    float acc[8] = {0.f, 0.f, 0.f, 0.f, 0.f, 0.f, 0.f, 0.f};
    const float* xp = x + (size_t)r0 * F_SZ + f0;     // block-uniform base
    const float* Tp = T + (size_t)f0 * C_SZ + t;

#pragma unroll 8
    for (int f = 0; f < 256; ++f) {
        const float tv = Tp[(size_t)f * C_SZ];
#pragma unroll
        for (int r = 0; r < 8; ++r)
            acc[r] += xp[r * F_SZ + f] * tv;          // uniform -> s_load
    }

    float* dst = ws2 + (size_t)ks * M_PLANE + k * (B_SZ * WSTR) + d;
#pragma unroll
    for (int r = 0; r < 8; ++r)
        dst[(r0 + r) * WSTR] = acc[r] * LOG2E;
}

// ---------------------------------------------------------------------------
// K2: pairwise features. grid 800 = 50 k x 16 j-splits; 512 threads (8 waves).
// Thread t owns rows i = t, t+512. j-tile (64 rows) staged SoA in LDS
// (q[d][64]) with the 2-plane sum folded in, so a 4-j chunk costs just 5
// broadcast ds_read_b128. Inner: 5 sub + 4 abs-add + exp2(-s) per pair.
// Features accumulated straight into out via atomicAdd (cols pre-zeroed).
// ---------------------------------------------------------------------------
__global__ __launch_bounds__(512) void pair_kernel(const float* __restrict__ ws2,
                                                   float* __restrict__ out) {
    const int k  = blockIdx.x >> 4;
    const int js = blockIdx.x & 15;
    const int j0 = js * 64;
    const int t  = threadIdx.x;

    __shared__ float q[5][64];               // SoA j-tile, 1.25 KB

    const float* pa = ws2 + (size_t)k * (B_SZ * WSTR);
    const float* pb = pa + (size_t)M_PLANE;

    if (t < 64) {                            // stage j-tile, sum planes, transpose
        const float* p0 = pa + (size_t)(j0 + t) * WSTR;
        const float* p1 = pb + (size_t)(j0 + t) * WSTR;
        const float4 a = *(const float4*)p0;
        const float4 b = *(const float4*)p1;
        q[0][t] = a.x + b.x;
        q[1][t] = a.y + b.y;
        q[2][t] = a.z + b.z;
        q[3][t] = a.w + b.w;
        q[4][t] = p0[4] + p1[4];
    }

    float m0[5], m1[5];                      // rows t, t+512 (load before sync)
    {
        const float* p0 = pa + (size_t)t * WSTR;
        const float* p1 = pb + (size_t)t * WSTR;
        const float4 a = *(const float4*)p0;
        const float4 b = *(const float4*)p1;
        m0[0] = a.x + b.x; m0[1] = a.y + b.y; m0[2] = a.z + b.z; m0[3] = a.w + b.w;
        m0[4] = p0[4] + p1[4];
    }
    {
        const float* p0 = pa + (size_t)(t + 512) * WSTR;
        const float* p1 = pb + (size_t)(t + 512) * WSTR;
        const float4 a = *(const float4*)p0;
        const float4 b = *(const float4*)p1;
        m1[0] = a.x + b.x; m1[1] = a.y + b.y; m1[2] = a.z + b.z; m1[3] = a.w + b.w;
        m1[4] = p0[4] + p1[4];
    }
    __syncthreads();

    float acc0 = 0.0f, acc1 = 0.0f;
#pragma unroll 4
    for (int ch = 0; ch < 16; ++ch) {
        const int jj = ch * 4;
        const float4 c0 = *(const float4*)&q[0][jj];   // broadcast b128 reads
        const float4 c1 = *(const float4*)&q[1][jj];
        const float4 c2 = *(const float4*)&q[2][jj];
        const float4 c3 = *(const float4*)&q[3][jj];
        const float4 c4 = *(const float4*)&q[4][jj];
#define PAIR_ONE(C)                                                              \
        {                                                                        \
            const float s0 = __builtin_fabsf(m0[0] - c0.C)                       \
                           + __builtin_fabsf(m0[1] - c1.C)                       \
                           + __builtin_fabsf(m0[2] - c2.C)                       \
                           + __builtin_fabsf(m0[3] - c3.C)                       \
                           + __builtin_fabsf(m0[4] - c4.C);                      \
            const float s1 = __builtin_fabsf(m1[0] - c0.C)                       \
                           + __builtin_fabsf(m1[1] - c1.C)                       \
                           + __builtin_fabsf(m1[2] - c2.C)                       \
                           + __builtin_fabsf(m1[3] - c3.C)                       \
                           + __builtin_fabsf(m1[4] - c4.C);                      \
            acc0 += __builtin_amdgcn_exp2f(-s0);                                 \
            acc1 += __builtin_amdgcn_exp2f(-s1);                                 \
        }
        PAIR_ONE(x) PAIR_ONE(y) PAIR_ONE(z) PAIR_ONE(w)
#undef PAIR_ONE
    }

    atomicAdd(&out[(size_t)t * OUTW + F_SZ + k], acc0);
    atomicAdd(&out[(size_t)(t + 512) * OUTW + F_SZ + k], acc1);
}

// ---------------------------------------------------------------------------
extern "C" void kernel_launch(void* const* d_in, const int* in_sizes, int n_in,
                              void* d_out, int out_size, void* d_ws, size_t ws_size,
                              hipStream_t stream) {
    const float* x = (const float*)d_in[0];   // [1024, 512]
    const float* T = (const float*)d_in[1];   // [512, 250]
    float* out = (float*)d_out;               // [1024, 562]
    float* ws2 = (float*)d_ws;                // 2 planes of [50][1024][8] fp32

    gemm_copy_kernel<<<384, 256, 0, stream>>>(x, T, ws2, out);
    pair_kernel<<<NK * JSPLIT, 512, 0, stream>>>(ws2, out);
}

// Round 4
// 88.951 us; speedup vs baseline: 1.0004x; 1.0004x over previous
//
#include <hip/hip_runtime.h>

#define B_SZ 1024
#define F_SZ 512
#define NK   50
#define KD   5
#define C_SZ 250            // NK*KD
#define OUTW 562            // F_SZ + NK
#define WSTR 8              // padded KD stride in M planes
#define M_PLANE (NK * B_SZ * WSTR)     // 409600 floats = 1.6384 MB per k-split plane
#define JSPLIT 16
#define LOG2E 1.44269504088896340736f

// ---------------------------------------------------------------------------
// K1: fused GEMM + copy. grid 384 x 256 threads.
//   blocks [0,256):   M = x @ T (fp32 vector), scaled by log2(e), written to
//                     two k-split planes ws2[ks][NK][B][WSTR] (no atomics).
//                     rt = blk&127 (8 rows), ks = blk>>7 (256 f each).
//                     x reads block-uniform -> s_loads; T reads coalesced.
//   blocks [256,384): copy x rows into out (float2) + zero 50 feature cols
//                     (pair_kernel accumulates into them atomically).
// ---------------------------------------------------------------------------
__global__ __launch_bounds__(256) void gemm_copy_kernel(const float* __restrict__ x,
                                                        const float* __restrict__ T,
                                                        float* __restrict__ ws2,
                                                        float* __restrict__ out) {
    const int t = threadIdx.x;

    if (blockIdx.x >= 256) {                 // ---- copy path: 8 rows/block
        const int b = blockIdx.x - 256;      // 0..127
#pragma unroll
        for (int r = 0; r < 8; ++r) {
            const int row = b * 8 + r;
            const float2* src = (const float2*)(x + (size_t)row * F_SZ);
            float2* dst = (float2*)(out + (size_t)row * OUTW);   // 8B aligned
            dst[t] = src[t];                 // 256 float2 = 512 floats
            if (t < NK) out[(size_t)row * OUTW + F_SZ + t] = 0.0f;
        }
        return;
    }

    // ---- gemm path
    const int rt = blockIdx.x & 127;         // row tile (8 rows)
    const int ks = blockIdx.x >> 7;          // k-split (0,1)
    if (t >= C_SZ) return;                   // no __syncthreads in this path
    const int r0 = rt * 8;
    const int f0 = ks * 256;
    const int k = t / KD;
    const int d = t - KD * k;

    float acc[8] = {0.f, 0.f, 0.f, 0.f, 0.f, 0.f, 0.f, 0.f};
    const float* xp = x + (size_t)r0 * F_SZ + f0;     // block-uniform base
    const float* Tp = T + (size_t)f0 * C_SZ + t;

#pragma unroll 8
    for (int f = 0; f < 256; ++f) {
        const float tv = Tp[(size_t)f * C_SZ];
#pragma unroll
        for (int r = 0; r < 8; ++r)
            acc[r] += xp[r * F_SZ + f] * tv;          // uniform -> s_load
    }

    float* dst = ws2 + (size_t)ks * M_PLANE + k * (B_SZ * WSTR) + d;
#pragma unroll
    for (int r = 0; r < 8; ++r)
        dst[(r0 + r) * WSTR] = acc[r] * LOG2E;
}

// ---------------------------------------------------------------------------
// K2: pairwise features. grid 800 = 50 k x 16 j-splits; 512 threads (8 waves).
// Thread t owns rows i = t, t+512. j-tile (64 rows) staged SoA in LDS
// (q[d][64]) with the 2-plane sum folded in, so a 4-j chunk costs just 5
// broadcast ds_read_b128. Inner: 5 sub + 4 abs-add + exp2(-s) per pair.
// Features accumulated straight into out via atomicAdd (cols pre-zeroed).
// ---------------------------------------------------------------------------
__global__ __launch_bounds__(512) void pair_kernel(const float* __restrict__ ws2,
                                                   float* __restrict__ out) {
    const int k  = blockIdx.x >> 4;
    const int js = blockIdx.x & 15;
    const int j0 = js * 64;
    const int t  = threadIdx.x;

    __shared__ float q[5][64];               // SoA j-tile, 1.25 KB

    const float* pa = ws2 + (size_t)k * (B_SZ * WSTR);
    const float* pb = pa + (size_t)M_PLANE;

    if (t < 64) {                            // stage j-tile, sum planes, transpose
        const float* p0 = pa + (size_t)(j0 + t) * WSTR;
        const float* p1 = pb + (size_t)(j0 + t) * WSTR;
        const float4 a = *(const float4*)p0;
        const float4 b = *(const float4*)p1;
        q[0][t] = a.x + b.x;
        q[1][t] = a.y + b.y;
        q[2][t] = a.z + b.z;
        q[3][t] = a.w + b.w;
        q[4][t] = p0[4] + p1[4];
    }

    float m0[5], m1[5];                      // rows t, t+512 (load before sync)
    {
        const float* p0 = pa + (size_t)t * WSTR;
        const float* p1 = pb + (size_t)t * WSTR;
        const float4 a = *(const float4*)p0;
        const float4 b = *(const float4*)p1;
        m0[0] = a.x + b.x; m0[1] = a.y + b.y; m0[2] = a.z + b.z; m0[3] = a.w + b.w;
        m0[4] = p0[4] + p1[4];
    }
    {
        const float* p0 = pa + (size_t)(t + 512) * WSTR;
        const float* p1 = pb + (size_t)(t + 512) * WSTR;
        const float4 a = *(const float4*)p0;
        const float4 b = *(const float4*)p1;
        m1[0] = a.x + b.x; m1[1] = a.y + b.y; m1[2] = a.z + b.z; m1[3] = a.w + b.w;
        m1[4] = p0[4] + p1[4];
    }
    __syncthreads();

    float acc0 = 0.0f, acc1 = 0.0f;
#pragma unroll 4
    for (int ch = 0; ch < 16; ++ch) {
        const int jj = ch * 4;
        const float4 c0 = *(const float4*)&q[0][jj];   // broadcast b128 reads
        const float4 c1 = *(const float4*)&q[1][jj];
        const float4 c2 = *(const float4*)&q[2][jj];
        const float4 c3 = *(const float4*)&q[3][jj];
        const float4 c4 = *(const float4*)&q[4][jj];
#define PAIR_ONE(C)                                                              \
        {                                                                        \
            const float s0 = __builtin_fabsf(m0[0] - c0.C)                       \
                           + __builtin_fabsf(m0[1] - c1.C)                       \
                           + __builtin_fabsf(m0[2] - c2.C)                       \
                           + __builtin_fabsf(m0[3] - c3.C)                       \
                           + __builtin_fabsf(m0[4] - c4.C);                      \
            const float s1 = __builtin_fabsf(m1[0] - c0.C)                       \
                           + __builtin_fabsf(m1[1] - c1.C)                       \
                           + __builtin_fabsf(m1[2] - c2.C)                       \
                           + __builtin_fabsf(m1[3] - c3.C)                       \
                           + __builtin_fabsf(m1[4] - c4.C);                      \
            acc0 += __builtin_amdgcn_exp2f(-s0);                                 \
            acc1 += __builtin_amdgcn_exp2f(-s1);                                 \
        }
        PAIR_ONE(x) PAIR_ONE(y) PAIR_ONE(z) PAIR_ONE(w)
#undef PAIR_ONE
    }

    atomicAdd(&out[(size_t)t * OUTW + F_SZ + k], acc0);
    atomicAdd(&out[(size_t)(t + 512) * OUTW + F_SZ + k], acc1);
}

// ---------------------------------------------------------------------------
extern "C" void kernel_launch(void* const* d_in, const int* in_sizes, int n_in,
                              void* d_out, int out_size, void* d_ws, size_t ws_size,
                              hipStream_t stream) {
    const float* x = (const float*)d_in[0];   // [1024, 512]
    const float* T = (const float*)d_in[1];   // [512, 250]
    float* out = (float*)d_out;               // [1024, 562]
    float* ws2 = (float*)d_ws;                // 2 planes of [50][1024][8] fp32

    gemm_copy_kernel<<<384, 256, 0, stream>>>(x, T, ws2, out);
    pair_kernel<<<NK * JSPLIT, 512, 0, stream>>>(ws2, out);
}

// Round 5
// 88.831 us; speedup vs baseline: 1.0018x; 1.0014x over previous
//
#include <hip/hip_runtime.h>

#define B_SZ 1024
#define F_SZ 512
#define NK   50
#define KD   5
#define C_SZ 250            // NK*KD
#define OUTW 562            // F_SZ + NK
#define WSTR 8              // padded KD stride in M planes
#define M_PLANE (NK * B_SZ * WSTR)     // 409600 floats = 1.6384 MB per k-split plane
#define JSPLIT 16
#define LOG2E 1.44269504088896340736f

// ---------------------------------------------------------------------------
// K1: fused GEMM + copy. grid 384 x 256 threads.
//   blocks [0,256):   M = x @ T (fp32 vector), scaled by log2(e), written to
//                     two k-split planes ws2[ks][NK][B][WSTR] (no atomics).
//                     rt = blk&127 (8 rows), ks = blk>>7 (256 f each).
//                     x reads block-uniform -> s_loads; T reads coalesced.
//   blocks [256,384): copy x rows into out (float2) + zero 50 feature cols
//                     (pair_kernel accumulates into them atomically).
// ---------------------------------------------------------------------------
__global__ __launch_bounds__(256) void gemm_copy_kernel(const float* __restrict__ x,
                                                        const float* __restrict__ T,
                                                        float* __restrict__ ws2,
                                                        float* __restrict__ out) {
    const int t = threadIdx.x;

    if (blockIdx.x >= 256) {                 // ---- copy path: 8 rows/block
        const int b = blockIdx.x - 256;      // 0..127
#pragma unroll
        for (int r = 0; r < 8; ++r) {
            const int row = b * 8 + r;
            const float2* src = (const float2*)(x + (size_t)row * F_SZ);
            float2* dst = (float2*)(out + (size_t)row * OUTW);   // 8B aligned
            dst[t] = src[t];                 // 256 float2 = 512 floats
            if (t < NK) out[(size_t)row * OUTW + F_SZ + t] = 0.0f;
        }
        return;
    }

    // ---- gemm path
    const int rt = blockIdx.x & 127;         // row tile (8 rows)
    const int ks = blockIdx.x >> 7;          // k-split (0,1)
    if (t >= C_SZ) return;                   // no __syncthreads in this path
    const int r0 = rt * 8;
    const int f0 = ks * 256;
    const int k = t / KD;
    const int d = t - KD * k;

    float acc[8] = {0.f, 0.f, 0.f, 0.f, 0.f, 0.f, 0.f, 0.f};
    const float* xp = x + (size_t)r0 * F_SZ + f0;     // block-uniform base
    const float* Tp = T + (size_t)f0 * C_SZ + t;

#pragma unroll 8
    for (int f = 0; f < 256; ++f) {
        const float tv = Tp[(size_t)f * C_SZ];
#pragma unroll
        for (int r = 0; r < 8; ++r)
            acc[r] += xp[r * F_SZ + f] * tv;          // uniform -> s_load
    }

    float* dst = ws2 + (size_t)ks * M_PLANE + k * (B_SZ * WSTR) + d;
#pragma unroll
    for (int r = 0; r < 8; ++r)
        dst[(r0 + r) * WSTR] = acc[r] * LOG2E;
}

// ---------------------------------------------------------------------------
// K2: pairwise features. grid 800 = 50 k x 16 j-splits; 512 threads (8 waves).
// Thread t owns rows i = t, t+512. j-tile (64 rows) staged SoA in LDS
// (q[d][64]) with the 2-plane sum folded in, so a 4-j chunk costs just 5
// broadcast ds_read_b128. Inner: 5 sub + 4 abs-add + exp2(-s) per pair.
// Features accumulated straight into out via atomicAdd (cols pre-zeroed).
// ---------------------------------------------------------------------------
__global__ __launch_bounds__(512) void pair_kernel(const float* __restrict__ ws2,
                                                   float* __restrict__ out) {
    const int k  = blockIdx.x >> 4;
    const int js = blockIdx.x & 15;
    const int j0 = js * 64;
    const int t  = threadIdx.x;

    __shared__ float q[5][64];               // SoA j-tile, 1.25 KB

    const float* pa = ws2 + (size_t)k * (B_SZ * WSTR);
    const float* pb = pa + (size_t)M_PLANE;

    if (t < 64) {                            // stage j-tile, sum planes, transpose
        const float* p0 = pa + (size_t)(j0 + t) * WSTR;
        const float* p1 = pb + (size_t)(j0 + t) * WSTR;
        const float4 a = *(const float4*)p0;
        const float4 b = *(const float4*)p1;
        q[0][t] = a.x + b.x;
        q[1][t] = a.y + b.y;
        q[2][t] = a.z + b.z;
        q[3][t] = a.w + b.w;
        q[4][t] = p0[4] + p1[4];
    }

    float m0[5], m1[5];                      // rows t, t+512 (load before sync)
    {
        const float* p0 = pa + (size_t)t * WSTR;
        const float* p1 = pb + (size_t)t * WSTR;
        const float4 a = *(const float4*)p0;
        const float4 b = *(const float4*)p1;
        m0[0] = a.x + b.x; m0[1] = a.y + b.y; m0[2] = a.z + b.z; m0[3] = a.w + b.w;
        m0[4] = p0[4] + p1[4];
    }
    {
        const float* p0 = pa + (size_t)(t + 512) * WSTR;
        const float* p1 = pb + (size_t)(t + 512) * WSTR;
        const float4 a = *(const float4*)p0;
        const float4 b = *(const float4*)p1;
        m1[0] = a.x + b.x; m1[1] = a.y + b.y; m1[2] = a.z + b.z; m1[3] = a.w + b.w;
        m1[4] = p0[4] + p1[4];
    }
    __syncthreads();

    float acc0 = 0.0f, acc1 = 0.0f;
#pragma unroll 4
    for (int ch = 0; ch < 16; ++ch) {
        const int jj = ch * 4;
        const float4 c0 = *(const float4*)&q[0][jj];   // broadcast b128 reads
        const float4 c1 = *(const float4*)&q[1][jj];
        const float4 c2 = *(const float4*)&q[2][jj];
        const float4 c3 = *(const float4*)&q[3][jj];
        const float4 c4 = *(const float4*)&q[4][jj];
#define PAIR_ONE(C)                                                              \
        {                                                                        \
            const float s0 = __builtin_fabsf(m0[0] - c0.C)                       \
                           + __builtin_fabsf(m0[1] - c1.C)                       \
                           + __builtin_fabsf(m0[2] - c2.C)                       \
                           + __builtin_fabsf(m0[3] - c3.C)                       \
                           + __builtin_fabsf(m0[4] - c4.C);                      \
            const float s1 = __builtin_fabsf(m1[0] - c0.C)                       \
                           + __builtin_fabsf(m1[1] - c1.C)                       \
                           + __builtin_fabsf(m1[2] - c2.C)                       \
                           + __builtin_fabsf(m1[3] - c3.C)                       \
                           + __builtin_fabsf(m1[4] - c4.C);                      \
            acc0 += __builtin_amdgcn_exp2f(-s0);                                 \
            acc1 += __builtin_amdgcn_exp2f(-s1);                                 \
        }
        PAIR_ONE(x) PAIR_ONE(y) PAIR_ONE(z) PAIR_ONE(w)
#undef PAIR_ONE
    }

    atomicAdd(&out[(size_t)t * OUTW + F_SZ + k], acc0);
    atomicAdd(&out[(size_t)(t + 512) * OUTW + F_SZ + k], acc1);
}

// ---------------------------------------------------------------------------
extern "C" void kernel_launch(void* const* d_in, const int* in_sizes, int n_in,
                              void* d_out, int out_size, void* d_ws, size_t ws_size,
                              hipStream_t stream) {
    const float* x = (const float*)d_in[0];   // [1024, 512]
    const float* T = (const float*)d_in[1];   // [512, 250]
    float* out = (float*)d_out;               // [1024, 562]
    float* ws2 = (float*)d_ws;                // 2 planes of [50][1024][8] fp32

    gemm_copy_kernel<<<384, 256, 0, stream>>>(x, T, ws2, out);
    pair_kernel<<<NK * JSPLIT, 512, 0, stream>>>(ws2, out);
}

// Round 6
// 88.049 us; speedup vs baseline: 1.0107x; 1.0089x over previous
//
#include <hip/hip_runtime.h>

#define B_SZ 1024
#define F_SZ 512
#define NK   50
#define KD   5
#define C_SZ 250            // NK*KD
#define OUTW 562            // F_SZ + NK
#define WSTR 8              // padded KD stride in M planes
#define M_PLANE (NK * B_SZ * WSTR)     // 409600 floats = 1.6384 MB per k-split plane
#define JSPLIT 16
#define LOG2E 1.44269504088896340736f

// ---------------------------------------------------------------------------
// K1: fused GEMM + copy. grid 384 x 256 threads.
//   blocks [0,256):   M = x @ T (fp32 vector), scaled by log2(e), written to
//                     two k-split planes ws2[ks][NK][B][WSTR] (no atomics).
//                     rt = blk&127 (8 rows), ks = blk>>7 (256 f each).
//                     x reads block-uniform -> s_loads; T reads coalesced.
//   blocks [256,384): copy x rows into out (float2) + zero 50 feature cols
//                     (pair_kernel accumulates into them atomically).
// ---------------------------------------------------------------------------
__global__ __launch_bounds__(256) void gemm_copy_kernel(const float* __restrict__ x,
                                                        const float* __restrict__ T,
                                                        float* __restrict__ ws2,
                                                        float* __restrict__ out) {
    const int t = threadIdx.x;

    if (blockIdx.x >= 256) {                 // ---- copy path: 8 rows/block
        const int b = blockIdx.x - 256;      // 0..127
#pragma unroll
        for (int r = 0; r < 8; ++r) {
            const int row = b * 8 + r;
            const float2* src = (const float2*)(x + (size_t)row * F_SZ);
            float2* dst = (float2*)(out + (size_t)row * OUTW);   // 8B aligned
            dst[t] = src[t];                 // 256 float2 = 512 floats
            if (t < NK) out[(size_t)row * OUTW + F_SZ + t] = 0.0f;
        }
        return;
    }

    // ---- gemm path
    const int rt = blockIdx.x & 127;         // row tile (8 rows)
    const int ks = blockIdx.x >> 7;          // k-split (0,1)
    if (t >= C_SZ) return;                   // no __syncthreads in this path
    const int r0 = rt * 8;
    const int f0 = ks * 256;
    const int k = t / KD;
    const int d = t - KD * k;

    float acc[8] = {0.f, 0.f, 0.f, 0.f, 0.f, 0.f, 0.f, 0.f};
    const float* xp = x + (size_t)r0 * F_SZ + f0;     // block-uniform base
    const float* Tp = T + (size_t)f0 * C_SZ + t;

#pragma unroll 8
    for (int f = 0; f < 256; ++f) {
        const float tv = Tp[(size_t)f * C_SZ];
#pragma unroll
        for (int r = 0; r < 8; ++r)
            acc[r] += xp[r * F_SZ + f] * tv;          // uniform -> s_load
    }

    float* dst = ws2 + (size_t)ks * M_PLANE + k * (B_SZ * WSTR) + d;
#pragma unroll
    for (int r = 0; r < 8; ++r)
        dst[(r0 + r) * WSTR] = acc[r] * LOG2E;
}

// ---------------------------------------------------------------------------
// K2: pairwise features. grid 800 = 50 k x 16 j-splits; 512 threads (8 waves).
// Thread t owns rows i = t, t+512. j-tile (64 rows) staged SoA in LDS
// (q[d][64]) with the 2-plane sum folded in, so a 4-j chunk costs just 5
// broadcast ds_read_b128. Inner: 5 sub + 4 abs-add + exp2(-s) per pair.
// Features accumulated straight into out via atomicAdd (cols pre-zeroed).
// ---------------------------------------------------------------------------
__global__ __launch_bounds__(512) void pair_kernel(const float* __restrict__ ws2,
                                                   float* __restrict__ out) {
    const int k  = blockIdx.x >> 4;
    const int js = blockIdx.x & 15;
    const int j0 = js * 64;
    const int t  = threadIdx.x;

    __shared__ float q[5][64];               // SoA j-tile, 1.25 KB

    const float* pa = ws2 + (size_t)k * (B_SZ * WSTR);
    const float* pb = pa + (size_t)M_PLANE;

    if (t < 64) {                            // stage j-tile, sum planes, transpose
        const float* p0 = pa + (size_t)(j0 + t) * WSTR;
        const float* p1 = pb + (size_t)(j0 + t) * WSTR;
        const float4 a = *(const float4*)p0;
        const float4 b = *(const float4*)p1;
        q[0][t] = a.x + b.x;
        q[1][t] = a.y + b.y;
        q[2][t] = a.z + b.z;
        q[3][t] = a.w + b.w;
        q[4][t] = p0[4] + p1[4];
    }

    float m0[5], m1[5];                      // rows t, t+512 (load before sync)
    {
        const float* p0 = pa + (size_t)t * WSTR;
        const float* p1 = pb + (size_t)t * WSTR;
        const float4 a = *(const float4*)p0;
        const float4 b = *(const float4*)p1;
        m0[0] = a.x + b.x; m0[1] = a.y + b.y; m0[2] = a.z + b.z; m0[3] = a.w + b.w;
        m0[4] = p0[4] + p1[4];
    }
    {
        const float* p0 = pa + (size_t)(t + 512) * WSTR;
        const float* p1 = pb + (size_t)(t + 512) * WSTR;
        const float4 a = *(const float4*)p0;
        const float4 b = *(const float4*)p1;
        m1[0] = a.x + b.x; m1[1] = a.y + b.y; m1[2] = a.z + b.z; m1[3] = a.w + b.w;
        m1[4] = p0[4] + p1[4];
    }
    __syncthreads();

    float acc0 = 0.0f, acc1 = 0.0f;
#pragma unroll 4
    for (int ch = 0; ch < 16; ++ch) {
        const int jj = ch * 4;
        const float4 c0 = *(const float4*)&q[0][jj];   // broadcast b128 reads
        const float4 c1 = *(const float4*)&q[1][jj];
        const float4 c2 = *(const float4*)&q[2][jj];
        const float4 c3 = *(const float4*)&q[3][jj];
        const float4 c4 = *(const float4*)&q[4][jj];
#define PAIR_ONE(C)                                                              \
        {                                                                        \
            const float s0 = __builtin_fabsf(m0[0] - c0.C)                       \
                           + __builtin_fabsf(m0[1] - c1.C)                       \
                           + __builtin_fabsf(m0[2] - c2.C)                       \
                           + __builtin_fabsf(m0[3] - c3.C)                       \
                           + __builtin_fabsf(m0[4] - c4.C);                      \
            const float s1 = __builtin_fabsf(m1[0] - c0.C)                       \
                           + __builtin_fabsf(m1[1] - c1.C)                       \
                           + __builtin_fabsf(m1[2] - c2.C)                       \
                           + __builtin_fabsf(m1[3] - c3.C)                       \
                           + __builtin_fabsf(m1[4] - c4.C);                      \
            acc0 += __builtin_amdgcn_exp2f(-s0);                                 \
            acc1 += __builtin_amdgcn_exp2f(-s1);                                 \
        }
        PAIR_ONE(x) PAIR_ONE(y) PAIR_ONE(z) PAIR_ONE(w)
#undef PAIR_ONE
    }

    atomicAdd(&out[(size_t)t * OUTW + F_SZ + k], acc0);
    atomicAdd(&out[(size_t)(t + 512) * OUTW + F_SZ + k], acc1);
}

// ---------------------------------------------------------------------------
extern "C" void kernel_launch(void* const* d_in, const int* in_sizes, int n_in,
                              void* d_out, int out_size, void* d_ws, size_t ws_size,
                              hipStream_t stream) {
    const float* x = (const float*)d_in[0];   // [1024, 512]
    const float* T = (const float*)d_in[1];   // [512, 250]
    float* out = (float*)d_out;               // [1024, 562]
    float* ws2 = (float*)d_ws;                // 2 planes of [50][1024][8] fp32

    gemm_copy_kernel<<<384, 256, 0, stream>>>(x, T, ws2, out);
    pair_kernel<<<NK * JSPLIT, 512, 0, stream>>>(ws2, out);
}

// Round 7
// 45.726 us; speedup vs baseline: 1.9461x; 1.9256x over previous
//
#include <hip/hip_runtime.h>

#define B_SZ 1024
#define F_SZ 512
#define NK   50
#define KD   5
#define C_SZ 250            // NK*KD
#define OUTW 562            // F_SZ + NK
#define WSTR 8              // padded KD stride in M planes
#define M_PLANE (NK * B_SZ * WSTR)      // 409600 floats per k-split plane
#define JSPLIT 16
#define PART_ELEMS (NK * JSPLIT * B_SZ) // 819200 floats = 3.28 MB
#define LOG2E 1.44269504088896340736f

// ---------------------------------------------------------------------------
// K1: fused GEMM + copy. grid 640 x 256 threads.
//   blocks [0,512):   M = x @ T (fp32 vector), scaled by log2(e), no atomics:
//                     two k-split planes ws2[ks][NK][B][WSTR].
//                     rt = blk&255 (4 rows), ks = blk>>8 (256 f each).
//                     x reads block-uniform -> s_load_dwordx8; T coalesced.
//   blocks [512,640): copy x rows into out (float2), 8 rows/block.
//                     zero_feat only for the atomic fallback mode.
// ---------------------------------------------------------------------------
__global__ __launch_bounds__(256) void gemm_copy_kernel(const float* __restrict__ x,
                                                        const float* __restrict__ T,
                                                        float* __restrict__ ws2,
                                                        float* __restrict__ out,
                                                        int zero_feat) {
    const int t = threadIdx.x;

    if (blockIdx.x >= 512) {                 // ---- copy path: 8 rows/block
        const int b = blockIdx.x - 512;      // 0..127
#pragma unroll
        for (int r = 0; r < 8; ++r) {
            const int row = b * 8 + r;
            const float2* src = (const float2*)(x + (size_t)row * F_SZ);
            float2* dst = (float2*)(out + (size_t)row * OUTW);   // 8B aligned
            dst[t] = src[t];                 // 256 float2 = 512 floats
            if (zero_feat && t < NK) out[(size_t)row * OUTW + F_SZ + t] = 0.0f;
        }
        return;
    }

    // ---- gemm path
    const int rt = blockIdx.x & 255;         // row tile (4 rows)
    const int ks = blockIdx.x >> 8;          // k-split (0,1)
    if (t >= C_SZ) return;                   // no __syncthreads in this path
    const int r0 = rt * 4;
    const int f0 = ks * 256;
    const int k = t / KD;
    const int d = t - KD * k;

    float acc[4] = {0.f, 0.f, 0.f, 0.f};
    const float* xp = x + (size_t)r0 * F_SZ + f0;     // block-uniform base
    const float* Tp = T + (size_t)f0 * C_SZ + t;

#pragma unroll 8
    for (int f = 0; f < 256; ++f) {
        const float tv = Tp[(size_t)f * C_SZ];
#pragma unroll
        for (int r = 0; r < 4; ++r)
            acc[r] += xp[r * F_SZ + f] * tv;          // uniform -> s_load
    }

    float* dst = ws2 + (size_t)ks * M_PLANE + k * (B_SZ * WSTR) + d;
#pragma unroll
    for (int r = 0; r < 4; ++r)
        dst[(r0 + r) * WSTR] = acc[r] * LOG2E;
}

// ---------------------------------------------------------------------------
// K2: pairwise features. grid 800 = 50 k x 16 j-splits; 256 threads (4 waves,
// 3200 waves machine-wide). Thread t owns rows i = t + 256r, r<4 (R=4
// amortizes each broadcast LDS read over 4 pairs). j-tile (64 rows) staged
// SoA (q[d][64]) with the 2-plane sum folded in: a 4-j chunk = 5 broadcast
// ds_read_b128. Per pair: 5 sub + 4 abs-add + exp2(-s) + acc.
// NO atomics on the fast path: per-jsplit partials, plain coalesced stores.
// ---------------------------------------------------------------------------
template <bool ATOMIC>
__global__ __launch_bounds__(256) void pair_kernel(const float* __restrict__ ws2,
                                                   float* __restrict__ dst) {
    const int k  = blockIdx.x >> 4;
    const int js = blockIdx.x & 15;
    const int j0 = js * 64;
    const int t  = threadIdx.x;

    __shared__ float q[5][64];               // SoA j-tile, 1.25 KB

    const float* pa = ws2 + (size_t)k * (B_SZ * WSTR);
    const float* pb = pa + (size_t)M_PLANE;

    if (t < 64) {                            // stage j-tile, sum planes, transpose
        const float* p0 = pa + (size_t)(j0 + t) * WSTR;
        const float* p1 = pb + (size_t)(j0 + t) * WSTR;
        const float4 a = *(const float4*)p0;
        const float4 b = *(const float4*)p1;
        q[0][t] = a.x + b.x;
        q[1][t] = a.y + b.y;
        q[2][t] = a.z + b.z;
        q[3][t] = a.w + b.w;
        q[4][t] = p0[4] + p1[4];
    }

    float m[4][5];                           // rows t + 256r (load before sync)
#pragma unroll
    for (int r = 0; r < 4; ++r) {
        const float* p0 = pa + (size_t)(t + 256 * r) * WSTR;
        const float* p1 = pb + (size_t)(t + 256 * r) * WSTR;
        const float4 a = *(const float4*)p0;
        const float4 b = *(const float4*)p1;
        m[r][0] = a.x + b.x; m[r][1] = a.y + b.y; m[r][2] = a.z + b.z;
        m[r][3] = a.w + b.w; m[r][4] = p0[4] + p1[4];
    }
    __syncthreads();

    float acc[4] = {0.0f, 0.0f, 0.0f, 0.0f};
#pragma unroll 2
    for (int ch = 0; ch < 16; ++ch) {
        const int jj = ch * 4;
        const float4 c0 = *(const float4*)&q[0][jj];   // broadcast b128 reads
        const float4 c1 = *(const float4*)&q[1][jj];
        const float4 c2 = *(const float4*)&q[2][jj];
        const float4 c3 = *(const float4*)&q[3][jj];
        const float4 c4 = *(const float4*)&q[4][jj];
#define PAIR_ONE(C)                                                              \
        _Pragma("unroll")                                                        \
        for (int r = 0; r < 4; ++r) {                                            \
            const float s = __builtin_fabsf(m[r][0] - c0.C)                      \
                          + __builtin_fabsf(m[r][1] - c1.C)                      \
                          + __builtin_fabsf(m[r][2] - c2.C)                      \
                          + __builtin_fabsf(m[r][3] - c3.C)                      \
                          + __builtin_fabsf(m[r][4] - c4.C);                     \
            acc[r] += __builtin_amdgcn_exp2f(-s);                                \
        }
        PAIR_ONE(x) PAIR_ONE(y) PAIR_ONE(z) PAIR_ONE(w)
#undef PAIR_ONE
    }

#pragma unroll
    for (int r = 0; r < 4; ++r) {
        const int i = t + 256 * r;
        if (ATOMIC) {
            atomicAdd(&dst[(size_t)i * OUTW + F_SZ + k], acc[r]);
        } else {
            dst[(size_t)(k * JSPLIT + js) * B_SZ + i] = acc[r];   // coalesced
        }
    }
}

// ---------------------------------------------------------------------------
// K3: fold the 16 j-split partials into out. grid 200 x 256.
// Reads coalesced (lanes contiguous in i); 16 L2-resident loads per output.
// ---------------------------------------------------------------------------
__global__ __launch_bounds__(256) void reduce_kernel(const float* __restrict__ part,
                                                     float* __restrict__ out) {
    const int k = blockIdx.x >> 2;
    const int i = ((blockIdx.x & 3) << 8) | threadIdx.x;
    float s = 0.0f;
#pragma unroll
    for (int sp = 0; sp < JSPLIT; ++sp)
        s += part[(size_t)(k * JSPLIT + sp) * B_SZ + i];
    out[(size_t)i * OUTW + F_SZ + k] = s;
}

// ---------------------------------------------------------------------------
extern "C" void kernel_launch(void* const* d_in, const int* in_sizes, int n_in,
                              void* d_out, int out_size, void* d_ws, size_t ws_size,
                              hipStream_t stream) {
    const float* x = (const float*)d_in[0];   // [1024, 512]
    const float* T = (const float*)d_in[1];   // [512, 250]
    float* out = (float*)d_out;               // [1024, 562]
    float* ws2 = (float*)d_ws;                // 2 planes of [50][1024][8] fp32
    float* part = ws2 + 2 * (size_t)M_PLANE;  // [50][16][1024]

    const size_t need_full = (size_t)(2 * M_PLANE + PART_ELEMS) * 4;  // 6.55 MB
    const int fast = (ws_size >= need_full);  // round-2 ran this mode -> ws fits

    gemm_copy_kernel<<<640, 256, 0, stream>>>(x, T, ws2, out, fast ? 0 : 1);

    if (fast) {
        pair_kernel<false><<<NK * JSPLIT, 256, 0, stream>>>(ws2, part);
        reduce_kernel<<<200, 256, 0, stream>>>(part, out);
    } else {
        pair_kernel<true><<<NK * JSPLIT, 256, 0, stream>>>(ws2, out);
    }
}